// Round 1
// baseline (1599.391 us; speedup 1.0000x reference)
//
#include <hip/hip_runtime.h>
#include <hip/hip_bf16.h>

#define T_TOK 8192
#define D_DIM 1024
#define F_DIM 4096
#define NE 8

#define BM 128
#define BN 128
#define BK 32

typedef _Float16 v8h __attribute__((ext_vector_type(8)));
typedef float f32x4 __attribute__((ext_vector_type(4)));

// ---------------- router: logits -> top2 -> scatter ----------------
__global__ void router_kernel(const float* __restrict__ x,
                              const float* __restrict__ Wgate,
                              int* __restrict__ cnt,
                              int* __restrict__ rows,
                              float* __restrict__ wts) {
    int t = blockIdx.x;
    int lane = threadIdx.x;
    const float* xr = x + (size_t)t * D_DIM;
    float acc[NE];
#pragma unroll
    for (int e = 0; e < NE; ++e) acc[e] = 0.f;
#pragma unroll
    for (int i = 0; i < D_DIM / 64; ++i) {
        int d = i * 64 + lane;
        float xv = xr[d];
#pragma unroll
        for (int e = 0; e < NE; ++e) acc[e] += xv * Wgate[e * D_DIM + d];
    }
#pragma unroll
    for (int off = 32; off > 0; off >>= 1) {
#pragma unroll
        for (int e = 0; e < NE; ++e) acc[e] += __shfl_xor(acc[e], off, 64);
    }
    if (lane == 0) {
        int e0 = 0;
#pragma unroll
        for (int e = 1; e < NE; ++e) if (acc[e] > acc[e0]) e0 = e;
        int e1 = (e0 == 0) ? 1 : 0;
#pragma unroll
        for (int e = 0; e < NE; ++e) if (e != e0 && acc[e] > acc[e1]) e1 = e;
        // renormalized top-2 softmax == softmax over the two logits
        float w0 = 1.f / (1.f + __expf(acc[e1] - acc[e0]));
        float w1 = 1.f - w0;
        int p0 = atomicAdd(&cnt[e0], 1);
        rows[e0 * T_TOK + p0] = 2 * t;       // hrow = 2*token + slot
        wts[e0 * T_TOK + p0] = w0;
        int p1 = atomicAdd(&cnt[e1], 1);
        rows[e1 * T_TOK + p1] = 2 * t + 1;
        wts[e1 * T_TOK + p1] = w1;
    }
}

// ---------------- x fp32 -> f16 ----------------
__global__ void xconv_kernel(const float* __restrict__ x, _Float16* __restrict__ Xh) {
    int i = blockIdx.x * blockDim.x + threadIdx.x;  // index in float4 units
    float4 v = ((const float4*)x)[i];
    union { _Float16 h[4]; uint2 u; } pk;
    pk.h[0] = (_Float16)v.x; pk.h[1] = (_Float16)v.y;
    pk.h[2] = (_Float16)v.z; pk.h[3] = (_Float16)v.w;
    *(uint2*)&Xh[(size_t)i * 4] = pk.u;
}

// ---------------- fused gate+up GEMM + silu*up*w -> H (f16) ----------------
__global__ __launch_bounds__(256)
void gateup_kernel(const _Float16* __restrict__ Xh,
                   const float* __restrict__ Wg,
                   const float* __restrict__ Wu,
                   const int* __restrict__ cnt,
                   const int* __restrict__ rows,
                   const float* __restrict__ wts,
                   _Float16* __restrict__ H) {
    int e = blockIdx.z;
    int c = cnt[e];
    int row0 = blockIdx.y * BM;
    if (row0 >= c) return;
    int col0 = blockIdx.x * BN;

    __shared__ __align__(16) _Float16 As[BM][BK];
    __shared__ __align__(16) _Float16 Bgs[BN][BK];
    __shared__ __align__(16) _Float16 Bus[BN][BK];
    __shared__ int hrow_s[BM];
    __shared__ float w_s[BM];

    int tid = threadIdx.x;
    int lane = tid & 63;
    int wave = tid >> 6;
    int wr = wave >> 1, wc = wave & 1;

    if (tid < BM) {
        int p = row0 + tid;
        if (p < c) { hrow_s[tid] = rows[e * T_TOK + p]; w_s[tid] = wts[e * T_TOK + p]; }
        else       { hrow_s[tid] = -1;                  w_s[tid] = 0.f; }
    }
    __syncthreads();

    int ar = tid >> 2;            // 0..63 (row within half-tile)
    int acoff = (tid & 3) * 8;    // 0,8,16,24 halves (16B each)
    int hr0 = hrow_s[ar],  hr1 = hrow_s[ar + 64];
    int tok0 = hr0 >> 1,   tok1 = hr1 >> 1;

    int bn = tid >> 3;            // 0..31
    int bkoff = (tid & 7) * 4;    // fp32 offset
    const float* wg0 = Wg + ((size_t)e * F_DIM + col0) * D_DIM;
    const float* wu0 = Wu + ((size_t)e * F_DIM + col0) * D_DIM;

    f32x4 accg[4][4], accu[4][4];
#pragma unroll
    for (int i = 0; i < 4; ++i)
#pragma unroll
        for (int j = 0; j < 4; ++j) { accg[i][j] = (f32x4)0.f; accu[i][j] = (f32x4)0.f; }

    int m16 = lane & 15, q8 = (lane >> 4) * 8;

    for (int k0 = 0; k0 < D_DIM; k0 += BK) {
        // stage A (gathered token rows, f16, 16B per thread per half)
        int4 av0 = make_int4(0, 0, 0, 0), av1 = make_int4(0, 0, 0, 0);
        if (hr0 >= 0) av0 = *(const int4*)&Xh[(size_t)tok0 * D_DIM + k0 + acoff];
        if (hr1 >= 0) av1 = *(const int4*)&Xh[(size_t)tok1 * D_DIM + k0 + acoff];
        *(int4*)&As[ar][acoff] = av0;
        *(int4*)&As[ar + 64][acoff] = av1;
        // stage B (fp32 -> f16 convert in flight)
#pragma unroll
        for (int p = 0; p < 4; ++p) {
            int n = p * 32 + bn;
            float4 g4 = *(const float4*)&wg0[(size_t)n * D_DIM + k0 + bkoff];
            float4 u4 = *(const float4*)&wu0[(size_t)n * D_DIM + k0 + bkoff];
            union { _Float16 h[4]; uint2 u; } pg, pu;
            pg.h[0] = (_Float16)g4.x; pg.h[1] = (_Float16)g4.y;
            pg.h[2] = (_Float16)g4.z; pg.h[3] = (_Float16)g4.w;
            pu.h[0] = (_Float16)u4.x; pu.h[1] = (_Float16)u4.y;
            pu.h[2] = (_Float16)u4.z; pu.h[3] = (_Float16)u4.w;
            *(uint2*)&Bgs[n][bkoff] = pg.u;
            *(uint2*)&Bus[n][bkoff] = pu.u;
        }
        __syncthreads();

        v8h af[4], bgf[4], buf_[4];
#pragma unroll
        for (int i = 0; i < 4; ++i)
            af[i] = *(const v8h*)&As[wr * 64 + i * 16 + m16][q8];
#pragma unroll
        for (int j = 0; j < 4; ++j) {
            bgf[j]  = *(const v8h*)&Bgs[wc * 64 + j * 16 + m16][q8];
            buf_[j] = *(const v8h*)&Bus[wc * 64 + j * 16 + m16][q8];
        }
#pragma unroll
        for (int i = 0; i < 4; ++i)
#pragma unroll
            for (int j = 0; j < 4; ++j) {
                accg[i][j] = __builtin_amdgcn_mfma_f32_16x16x32_f16(af[i], bgf[j], accg[i][j], 0, 0, 0);
                accu[i][j] = __builtin_amdgcn_mfma_f32_16x16x32_f16(af[i], buf_[j], accu[i][j], 0, 0, 0);
            }
        __syncthreads();
    }

    // epilogue: h = silu(g)*u*w -> H[hrow][col] (f16)
    int q = lane >> 4, cl = lane & 15;
#pragma unroll
    for (int i = 0; i < 4; ++i) {
#pragma unroll
        for (int r4 = 0; r4 < 4; ++r4) {
            int r = wr * 64 + i * 16 + q * 4 + r4;
            int hr = hrow_s[r];
            if (hr < 0) continue;
            float w = w_s[r];
#pragma unroll
            for (int j = 0; j < 4; ++j) {
                int col = col0 + wc * 64 + j * 16 + cl;
                float g = accg[i][j][r4];
                float u = accu[i][j][r4];
                float h = g / (1.f + __expf(-g)) * u * w;
                H[(size_t)hr * F_DIM + col] = (_Float16)h;
            }
        }
    }
}

// ---------------- down GEMM: H @ Wd^T -> O (fp32, slot-indexed) ----------------
__global__ __launch_bounds__(256)
void down_kernel(const _Float16* __restrict__ H,
                 const float* __restrict__ Wd,
                 const int* __restrict__ cnt,
                 const int* __restrict__ rows,
                 float* __restrict__ O) {
    int e = blockIdx.z;
    int c = cnt[e];
    int row0 = blockIdx.y * BM;
    if (row0 >= c) return;
    int col0 = blockIdx.x * BN;

    __shared__ __align__(16) _Float16 As[BM][BK];
    __shared__ __align__(16) _Float16 Bs[BN][BK];
    __shared__ int hrow_s[BM];

    int tid = threadIdx.x;
    int lane = tid & 63;
    int wave = tid >> 6;
    int wr = wave >> 1, wc = wave & 1;

    if (tid < BM) {
        int p = row0 + tid;
        hrow_s[tid] = (p < c) ? rows[e * T_TOK + p] : -1;
    }
    __syncthreads();

    int ar = tid >> 2;
    int acoff = (tid & 3) * 8;
    int hr0 = hrow_s[ar], hr1 = hrow_s[ar + 64];

    int bn = tid >> 3;
    int bkoff = (tid & 7) * 4;
    const float* wd0 = Wd + ((size_t)e * D_DIM + col0) * F_DIM;

    f32x4 acc[4][4];
#pragma unroll
    for (int i = 0; i < 4; ++i)
#pragma unroll
        for (int j = 0; j < 4; ++j) acc[i][j] = (f32x4)0.f;

    int m16 = lane & 15, q8 = (lane >> 4) * 8;

    for (int k0 = 0; k0 < F_DIM; k0 += BK) {
        int4 av0 = make_int4(0, 0, 0, 0), av1 = make_int4(0, 0, 0, 0);
        if (hr0 >= 0) av0 = *(const int4*)&H[(size_t)hr0 * F_DIM + k0 + acoff];
        if (hr1 >= 0) av1 = *(const int4*)&H[(size_t)hr1 * F_DIM + k0 + acoff];
        *(int4*)&As[ar][acoff] = av0;
        *(int4*)&As[ar + 64][acoff] = av1;
#pragma unroll
        for (int p = 0; p < 4; ++p) {
            int n = p * 32 + bn;
            float4 b4 = *(const float4*)&wd0[(size_t)n * F_DIM + k0 + bkoff];
            union { _Float16 h[4]; uint2 u; } pb;
            pb.h[0] = (_Float16)b4.x; pb.h[1] = (_Float16)b4.y;
            pb.h[2] = (_Float16)b4.z; pb.h[3] = (_Float16)b4.w;
            *(uint2*)&Bs[n][bkoff] = pb.u;
        }
        __syncthreads();

        v8h af[4], bf[4];
#pragma unroll
        for (int i = 0; i < 4; ++i)
            af[i] = *(const v8h*)&As[wr * 64 + i * 16 + m16][q8];
#pragma unroll
        for (int j = 0; j < 4; ++j)
            bf[j] = *(const v8h*)&Bs[wc * 64 + j * 16 + m16][q8];
#pragma unroll
        for (int i = 0; i < 4; ++i)
#pragma unroll
            for (int j = 0; j < 4; ++j)
                acc[i][j] = __builtin_amdgcn_mfma_f32_16x16x32_f16(af[i], bf[j], acc[i][j], 0, 0, 0);
        __syncthreads();
    }

    int q = lane >> 4, cl = lane & 15;
#pragma unroll
    for (int i = 0; i < 4; ++i) {
#pragma unroll
        for (int r4 = 0; r4 < 4; ++r4) {
            int r = wr * 64 + i * 16 + q * 4 + r4;
            int hr = hrow_s[r];
            if (hr < 0) continue;
#pragma unroll
            for (int j = 0; j < 4; ++j) {
                int col = col0 + wc * 64 + j * 16 + cl;
                O[(size_t)hr * D_DIM + col] = acc[i][j][r4];
            }
        }
    }
}

// ---------------- combine: out[t] = O[2t] + O[2t+1] ----------------
__global__ void combine_kernel(const float* __restrict__ O, float* __restrict__ out) {
    int t = blockIdx.x;
    int d = threadIdx.x;  // float4 index, 256 per row
    const float4* a = (const float4*)(O + (size_t)(2 * t) * D_DIM);
    const float4* b = (const float4*)(O + (size_t)(2 * t + 1) * D_DIM);
    float4 va = a[d], vb = b[d];
    float4 r; r.x = va.x + vb.x; r.y = va.y + vb.y; r.z = va.z + vb.z; r.w = va.w + vb.w;
    ((float4*)(out + (size_t)t * D_DIM))[d] = r;
}

extern "C" void kernel_launch(void* const* d_in, const int* in_sizes, int n_in,
                              void* d_out, int out_size, void* d_ws, size_t ws_size,
                              hipStream_t stream) {
    const float* x     = (const float*)d_in[0];
    const float* Wgate = (const float*)d_in[1];
    const float* Wg    = (const float*)d_in[2];
    const float* Wu    = (const float*)d_in[3];
    const float* Wd    = (const float*)d_in[4];
    float* out = (float*)d_out;

    char* w = (char*)d_ws;
    // workspace layout (total ~218.6 MB)
    int*      cnt  = (int*)w;                          // 32 B (zeroed below)
    int*      rows = (int*)(w + 1024);                 // 8*8192*4 = 256 KB
    float*    wts  = (float*)(w + 263168);             // 256 KB
    _Float16* Xh   = (_Float16*)(w + 525312);          // 16 MB
    _Float16* H    = (_Float16*)(w + 17302528);        // 16384*4096*2 = 128 MB
    float*    O    = (float*)(w + 151520256);          // 16384*1024*4 = 64 MB

    hipMemsetAsync(w, 0, 1024, stream);  // zero expert counters

    router_kernel<<<T_TOK, 64, 0, stream>>>(x, Wgate, cnt, rows, wts);
    xconv_kernel<<<(T_TOK * D_DIM / 4) / 256, 256, 0, stream>>>(x, Xh);
    gateup_kernel<<<dim3(F_DIM / BN, T_TOK / BM, NE), 256, 0, stream>>>(
        Xh, Wg, Wu, cnt, rows, wts, H);
    down_kernel<<<dim3(D_DIM / BN, T_TOK / BM, NE), 256, 0, stream>>>(
        H, Wd, cnt, rows, O);
    combine_kernel<<<T_TOK, 256, 0, stream>>>(O, out);
}